// Round 19
// baseline (143.984 us; speedup 1.0000x reference)
//
#include <hip/hip_runtime.h>
#include <hip/hip_bf16.h>
#include <stdint.h>

#define B_ 4
#define N_ 1024
#define C_ 768
#define H_ 12
#define D_ 64

typedef unsigned short u16;
typedef unsigned char u8;
typedef __attribute__((ext_vector_type(8))) short bf16x8;
typedef __attribute__((ext_vector_type(4))) float f32x4;

#define AS1 __attribute__((address_space(1)))
#define AS3 __attribute__((address_space(3)))

__device__ __forceinline__ u16 f2b(float f) {
    union { float f; uint32_t u; } x; x.f = f;
    uint32_t r = x.u + 0x7fffu + ((x.u >> 16) & 1u);
    return (u16)(r >> 16);
}
__device__ __forceinline__ float b2f(u16 b) {
    union { uint32_t u; float f; } x; x.u = ((uint32_t)b) << 16;
    return x.f;
}
// packed f32->bf16 pair (RNE, same as f2b); dst.lo=cvt(lo), dst.hi=cvt(hi)
__device__ __forceinline__ uint32_t cvtpk(float lo, float hi) {
    uint32_t r;
    asm("v_cvt_pk_bf16_f32 %0, %1, %2" : "=v"(r) : "v"(lo), "v"(hi));
    return r;
}
// raw 2^x: one v_exp_f32 (no libm denormal fixup, no mul). Valid: |x| small.
__device__ __forceinline__ float exp2_fast(float x) {
    float r;
    asm("v_exp_f32 %0, %1" : "=v"(r) : "v"(x));
    return r;
}

__device__ __forceinline__ void gload16(const void* g, void* lds) {
    __builtin_amdgcn_global_load_lds((const AS1 uint32_t*)g, (AS3 uint32_t*)lds, 16, 0, 0);
}

// Stage a (rows x 64) bf16 tile from row-major src (leading dim ld, elements)
// into LDS. LDS layout: row stride 128B, 16B-slot XOR-swizzle byte^=(row&7)<<4.
__device__ __forceinline__ void stage_tile(const u16* __restrict__ g, int ld,
                                           u16* lds, int rows, int w, int l) {
    int nchunk = rows >> 3;              // 1KB chunks (8 rows each)
    for (int j = w; j < nchunk; j += 4) {
        int base = j << 10;              // wave-uniform LDS byte base
        int lanebyte = base + (l << 4);
        int row  = lanebyte >> 7;
        int slot = ((lanebyte >> 4) & 7) ^ (row & 7);
        const u16* src = g + row * ld + (slot << 3);
        gload16(src, (char*)lds + base);
    }
}

__device__ __forceinline__ bf16x8 frag_ld(const u16* lds, int row, int k) {
    int byte = (row << 7) + (k << 1);
    byte ^= (row & 7) << 4;
    return *(const bf16x8*)((const char*)lds + byte);
}

__device__ __forceinline__ f32x4 mfma_bf16(bf16x8 a, bf16x8 b, f32x4 c) {
    return __builtin_amdgcn_mfma_f32_16x16x32_bf16(a, b, c, 0, 0, 0);
}

// ---------------- merged input prep: cvt(x) + transcvt(Wqkv) + transcvt(Wproj) --

__global__ void k_prep(const float* __restrict__ x, u16* __restrict__ xb,
                       const float* __restrict__ Wqkv, u16* __restrict__ WqkvT,
                       const float* __restrict__ Wproj, u16* __restrict__ WprojT) {
    __shared__ float t[32][33];
    int blk = blockIdx.x;
    int tid = threadIdx.x;
    if (blk < 3072) {                    // cvt: x f32 -> xb bf16
        int i = blk * 256 + tid;
        float4 v = ((const float4*)x)[i];
        ushort4 o;
        o.x = f2b(v.x); o.y = f2b(v.y); o.z = f2b(v.z); o.w = f2b(v.w);
        ((ushort4*)xb)[i] = o;
        return;
    }
    const float* in; u16* outb; int R, Cc, bx, by;
    if (blk < 3072 + 1728) {             // Wqkv [768][2304] -> [2304][768] bf16
        int tq = blk - 3072;
        in = Wqkv; outb = WqkvT; R = C_; Cc = 3 * C_; bx = tq % 72; by = tq / 72;
    } else {                             // Wproj [768][768] -> transposed bf16
        int tq = blk - 4800;
        in = Wproj; outb = WprojT; R = C_; Cc = C_; bx = tq % 24; by = tq / 24;
    }
    int bc = bx * 32, br = by * 32;
    for (int i = 0; i < 4; i++) {
        int idx = i * 256 + tid; int r = idx >> 5, c = idx & 31;
        t[r][c] = in[(size_t)(br + r) * Cc + bc + c];
    }
    __syncthreads();
    for (int i = 0; i < 4; i++) {
        int idx = i * 256 + tid; int c = idx >> 5, r = idx & 31;
        outb[(size_t)(bc + c) * R + br + r] = f2b(t[r][c]);
    }
}

// ---------------- GEMM: qkv = x @ W_qkv ----------------
// qkv buffer holds ONLY q,k (ld = 2C, q pre-scaled by 1/8). v-columns
// (col >= 2C, block-uniform branch) are written DIRECTLY TRANSPOSED to
// vT[b][h][dd][n] via ushort4 -- no separate transpose kernel.

__global__ __launch_bounds__(256, 2)
void k_gemm_qkv(const u16* __restrict__ xb, const u16* __restrict__ WT,
                u16* __restrict__ qkv, u16* __restrict__ vT) {
    __shared__ __attribute__((aligned(128))) u16 As[128 * 64];
    __shared__ __attribute__((aligned(128))) u16 Bs[128 * 64];
    int tid = threadIdx.x, w = tid >> 6, l = tid & 63;
    int swz = (blockIdx.x & 7) * 72 + (blockIdx.x >> 3);    // bijective (576%8==0)
    int row0 = (swz / 18) * 128, col0 = (swz % 18) * 128;
    f32x4 acc[4][4] = {};
    int wr = (w >> 1) * 64, wc = (w & 1) * 64;
    int fr = l & 15, fq = l >> 4;
    for (int k0 = 0; k0 < C_; k0 += 64) {
        stage_tile(xb + (size_t)row0 * C_ + k0, C_, As, 128, w, l);
        stage_tile(WT + (size_t)col0 * C_ + k0, C_, Bs, 128, w, l);
        __syncthreads();
        #pragma unroll
        for (int kk = 0; kk < 64; kk += 32) {
            bf16x8 af[4], bfr[4];
            #pragma unroll
            for (int i = 0; i < 4; i++) af[i] = frag_ld(As, wr + i * 16 + fr, kk + fq * 8);
            #pragma unroll
            for (int j = 0; j < 4; j++) bfr[j] = frag_ld(Bs, wc + j * 16 + fr, kk + fq * 8);
            #pragma unroll
            for (int i = 0; i < 4; i++)
                #pragma unroll
                for (int j = 0; j < 4; j++)
                    acc[i][j] = mfma_bf16(af[i], bfr[j], acc[i][j]);
        }
        __syncthreads();
    }
    #pragma unroll
    for (int i = 0; i < 4; i++) {
        #pragma unroll
        for (int j = 0; j < 4; j++) {
            int col = col0 + wc + j * 16 + fr;
            int rowb = row0 + wr + i * 16 + fq * 4;
            if (col < 2 * C_) {                     // q,k -> qkv (ld 2C)
                float s = (col < C_) ? 0.125f : 1.0f;
                #pragma unroll
                for (int r = 0; r < 4; r++)
                    qkv[(size_t)(rowb + r) * (2 * C_) + col] = f2b(acc[i][j][r] * s);
            } else {                                // v -> vT transposed
                int col1 = col - 2 * C_;
                int hh = col1 >> 6, dd = col1 & 63;
                int bb = rowb >> 10, n0 = rowb & 1023;
                ushort4 vv;
                #pragma unroll
                for (int r = 0; r < 4; r++) ((u16*)&vv)[r] = f2b(acc[i][j][r]);
                *(ushort4*)(vT + ((size_t)(bb * H_ + hh) * D_ + dd) * N_ + n0) = vv;
            }
        }
    }
}

// ---------------- GEMM: S[b][n][h][m] = q . k  (S in FP8 e4m3) ----------------
// S values are tiny (sigma ~0.3, |S| <= ~2): e4m3 rel-err ~6%, and mix1
// multiplies by Wl~0.02 -> logit error ~0.01 abs -> negligible on softmax
// (validated r17: absmax unchanged at 0.03125). NOTE r18 lesson: fp8 is
// admissible ONLY here (softmax-damped); Pw/z must stay bf16 (direct path).

__global__ __launch_bounds__(256, 2)
void k_gemm_qk(const u16* __restrict__ qkv, u8* __restrict__ S8) {
    __shared__ __attribute__((aligned(128))) u16 pool[128 * 132];   // 33.8KB
    u16* As = pool;
    u16* Bs = pool + 128 * 64;
    int tid = threadIdx.x, w = tid >> 6, l = tid & 63;
    int blk = (blockIdx.x & 7) * 384 + (blockIdx.x >> 3);   // bijective (3072%8==0)
    int bh = blk >> 6, t = blk & 63;
    int b = bh / H_, h = bh % H_;
    int tm = t >> 3, tn = t & 7;
    const u16* qbase = qkv + (size_t)(b * N_) * (2 * C_) + h * 64;
    const u16* kbase = qkv + (size_t)(b * N_) * (2 * C_) + C_ + h * 64;
    f32x4 acc[4][4] = {};
    int wr = (w >> 1) * 64, wc = (w & 1) * 64;
    int fr = l & 15, fq = l >> 4;
    stage_tile(qbase + (size_t)(tm * 128) * (2 * C_), 2 * C_, As, 128, w, l);
    stage_tile(kbase + (size_t)(tn * 128) * (2 * C_), 2 * C_, Bs, 128, w, l);
    __syncthreads();
    #pragma unroll
    for (int kk = 0; kk < 64; kk += 32) {
        bf16x8 af[4], bfr[4];
        #pragma unroll
        for (int i = 0; i < 4; i++) af[i] = frag_ld(As, wr + i * 16 + fr, kk + fq * 8);
        #pragma unroll
        for (int j = 0; j < 4; j++) bfr[j] = frag_ld(Bs, wc + j * 16 + fr, kk + fq * 8);
        #pragma unroll
        for (int i = 0; i < 4; i++)
            #pragma unroll
            for (int j = 0; j < 4; j++)
                acc[i][j] = mfma_bf16(af[i], bfr[j], acc[i][j]);
    }
    __syncthreads();                       // all frag ds_reads done; reuse pool
    u8* Cs = (u8*)pool;                    // [128][136] u8 (8B-aligned rows)
    #pragma unroll
    for (int i = 0; i < 4; i++) {
        #pragma unroll
        for (int j = 0; j < 4; j++) {
            int lcol = wc + j * 16 + fr;
            int lrow0 = wr + i * 16 + fq * 4;
            uint32_t w01 = __builtin_amdgcn_cvt_pk_fp8_f32(acc[i][j][0], acc[i][j][1], 0, false);
            uint32_t w23 = __builtin_amdgcn_cvt_pk_fp8_f32(acc[i][j][2], acc[i][j][3], 0, false);
            Cs[(lrow0 + 0) * 136 + lcol] = (u8)w01;
            Cs[(lrow0 + 1) * 136 + lcol] = (u8)(w01 >> 8);
            Cs[(lrow0 + 2) * 136 + lcol] = (u8)w23;
            Cs[(lrow0 + 3) * 136 + lcol] = (u8)(w23 >> 8);
        }
    }
    __syncthreads();
    // 128 rows x 16 8B-chunks = 2048 chunks / 256 thr = 8 passes
    for (int q = 0; q < 8; q++) {
        int idx = q * 256 + tid;
        int lrow = idx >> 4, lc = idx & 15;
        uint2 v = *(const uint2*)&Cs[lrow * 136 + lc * 8];
        *(uint2*)(S8 + ((size_t)(b * N_ + tm * 128 + lrow) * H_ + h) * N_
                     + tn * 128 + lc * 8) = v;
    }
}

// ---------------- fused: W_l head-mix + softmax + W_w head-mix ----------------
// r19 = r17 (passed, 143.3us) + s_setprio(1) around the MFMA/exp clusters
// (T5: mix is attn-like -- blocks at staggered phases, no lockstep; compute
// waves get scheduler preference over staging waves). No math changes.

__global__ __launch_bounds__(256)
void k_mix_softmax(const u8* __restrict__ S8, u16* __restrict__ Pw,
                   const float* __restrict__ Wl, const float* __restrict__ Ww,
                   const float* __restrict__ bw) {
    __shared__ __attribute__((aligned(16))) char mixpool[4][8192];  // 32KB
    __shared__ float Zl[4][16];
    __shared__ float sWl[144], sWw[144], sbw16[16];
    int tid = threadIdx.x;
    int wv = tid >> 6, l = tid & 63;
    int m_l = l & 15, gr = l >> 4;
    if (tid < 144) { sWl[tid] = Wl[tid]; sWw[tid] = Ww[tid]; }
    if (tid < 16) sbw16[tid] = (tid < 12) ? bw[tid] : 0.f;
    __syncthreads();

    int blk = blockIdx.x;
    int b = blk >> 10, n = blk & 1023;
    const u8* srow = S8 + ((size_t)(b * N_ + n) * H_) * N_ + wv * 256;
    char* wvbase = &mixpool[wv][0];

    // ---- staging: lane l covers m = p*64+l; one b64 (8 fp8) per (m, plane) ----
    for (int p = 0; p < 4; p++) {
        int m = p * 64 + l;
        #pragma unroll
        for (int hb = 0; hb < 2; hb++) {
            uint2 pk;
            u8* pb = (u8*)&pk;
            #pragma unroll
            for (int j = 0; j < 8; j++) {
                int h = hb * 8 + j;
                pb[j] = (h < 12) ? srow[(size_t)h * N_ + m] : (u8)0;
            }
            *(uint2*)(wvbase + hb * 2048 + m * 8) = pk;
        }
    }

    // A1 frag: Wl^T * log2e in fp8, zero-padded to 16x32 (k = byte index)
    float wv8[8];
    #pragma unroll
    for (int j = 0; j < 8; j++) {
        int h = gr * 8 + j;
        int ok = (m_l < 12) & (h < 12);
        wv8[j] = ok ? (sWl[ok ? (h * 12 + m_l) : 0] * 1.44269504089f) : 0.f;
    }
    uint32_t a1lo = 0, a1hi = 0;
    a1lo = __builtin_amdgcn_cvt_pk_fp8_f32(wv8[0], wv8[1], a1lo, false);
    a1lo = __builtin_amdgcn_cvt_pk_fp8_f32(wv8[2], wv8[3], a1lo, true);
    a1hi = __builtin_amdgcn_cvt_pk_fp8_f32(wv8[4], wv8[5], a1hi, false);
    a1hi = __builtin_amdgcn_cvt_pk_fp8_f32(wv8[6], wv8[7], a1hi, true);
    long a1 = ((long)a1hi << 32) | (long)a1lo;

    // mix1 (fp8 MFMA) + 2^x + Z-accumulate; E kept in registers (bf16 pairs)
    float z0 = 0.f, z1 = 0.f, z2 = 0.f, z3 = 0.f;
    uint32_t E0[16], E1[16];
    __builtin_amdgcn_s_setprio(1);
    #pragma unroll
    for (int grp = 0; grp < 16; grp++) {
        long bs = 0;
        if (gr < 2) bs = *(const long*)(wvbase + gr * 2048 + (grp * 16 + m_l) * 8);
        f32x4 c = {0.f, 0.f, 0.f, 0.f};
        c = __builtin_amdgcn_mfma_f32_16x16x32_fp8_fp8(a1, bs, c, 0, 0, 0);
        float e0 = exp2_fast(c[0]), e1 = exp2_fast(c[1]);
        float e2 = exp2_fast(c[2]), e3 = exp2_fast(c[3]);
        z0 += e0; z1 += e1; z2 += e2; z3 += e3;
        E0[grp] = cvtpk(e0, e1);
        E1[grp] = cvtpk(e2, e3);
    }
    __builtin_amdgcn_s_setprio(0);

    // Z: reduce over 16 m-lanes, publish per-wave, sum across waves
    #pragma unroll
    for (int off = 1; off < 16; off <<= 1) {
        z0 += __shfl_xor(z0, off);
        z1 += __shfl_xor(z1, off);
        z2 += __shfl_xor(z2, off);
        z3 += __shfl_xor(z3, off);
    }
    if (m_l == 0) {
        Zl[wv][gr * 4 + 0] = z0; Zl[wv][gr * 4 + 1] = z1;
        Zl[wv][gr * 4 + 2] = z2; Zl[wv][gr * 4 + 3] = z3;
    }
    __syncthreads();

    // A2 frag: Ww^T / Z_h, zero-padded (bf16 -- mix2 unchanged)
    bf16x8 a2;
    #pragma unroll
    for (int j = 0; j < 8; j++) {
        int h = gr * 8 + j;
        float v = 0.f;
        if ((m_l < 12) & (h < 12)) {
            float zz = Zl[0][h] + Zl[1][h] + Zl[2][h] + Zl[3][h];
            v = sWw[h * 12 + m_l] / zz;
        }
        ((u16*)&a2)[j] = f2b(v);
    }

    // mix2: B-frag gathered from E regs via 4 shuffles (C<->B duality)
    f32x4 cb;
    cb[0] = sbw16[gr * 4 + 0]; cb[1] = sbw16[gr * 4 + 1];
    cb[2] = sbw16[gr * 4 + 2]; cb[3] = sbw16[gr * 4 + 3];
    int la = m_l + (((2 * gr) & 3) << 4);
    int lb = m_l + (((2 * gr + 1) & 3) << 4);
    u16* Pb = (u16*)wvbase;                    // overlay: staging dead after mix1
    __builtin_amdgcn_s_setprio(1);
    #pragma unroll
    for (int grp = 0; grp < 16; grp++) {
        union { int4 i4; bf16x8 v; } u;
        u.i4.x = __shfl((int)E0[grp], la);
        u.i4.y = __shfl((int)E1[grp], la);
        u.i4.z = __shfl((int)E0[grp], lb);
        u.i4.w = __shfl((int)E1[grp], lb);
        f32x4 c = cb;
        c = mfma_bf16(a2, u.v, c);
        if (gr < 3) {
            uint32_t w01 = cvtpk(c[0], c[1]);
            uint32_t w23 = cvtpk(c[2], c[3]);
            int g0 = gr * 4, mm = grp * 16 + m_l;
            Pb[(g0 + 0) * 276 + mm] = (u16)w01;
            Pb[(g0 + 1) * 276 + mm] = (u16)(w01 >> 16);
            Pb[(g0 + 2) * 276 + mm] = (u16)w23;
            Pb[(g0 + 3) * 276 + mm] = (u16)(w23 >> 16);
        }
    }
    __builtin_amdgcn_s_setprio(0);

    // vectorized Pw store: 12 rows x 512B per wave (wave-local, no barrier)
    for (int g = 0; g < 12; g++) {
        ushort4 v = *(const ushort4*)&Pb[g * 276 + l * 4];
        *(ushort4*)(Pw + ((size_t)(b * H_ + g) * N_ + n) * N_ + wv * 256 + l * 4) = v;
    }
}

// ---------------- GEMM: MODE 0: u = Pw @ v, epilogue z = (1-2l)v + 3l*u -> zT
//                        MODE 1: o = Pw @ z (B = zT), writes o[b,n,h*64+d] ----------------
// algebra: out_head = (1-2l)*Pw@v + 3l*Pw@(Pw@v) = Pw @ z,  z=(1-2l)v+3l*u
// 64-row tiles (tm 0..15): grid 768 blocks, LDS 16KB, ~3 blocks/CU.
// XCD-aware chunked swizzle (T1, proven r15). bf16 throughout (r18 lesson).

template <int MODE>
__global__ __launch_bounds__(256, 2)
void k_gemm_av(const u16* __restrict__ Pw, const u16* __restrict__ BT,
               u16* __restrict__ outp, const float* __restrict__ lamb) {
    __shared__ __attribute__((aligned(128))) u16 As[64 * 64];
    __shared__ __attribute__((aligned(128))) u16 Bs[64 * 64];
    int tid = threadIdx.x, w = tid >> 6, l = tid & 63;
    int blk = (blockIdx.x & 7) * 96 + (blockIdx.x >> 3);    // bijective (768%8==0)
    int bh = blk >> 4, tm = blk & 15;
    int b = bh / H_, h = bh % H_;
    const u16* Abase = Pw + ((size_t)bh * N_ + tm * 64) * N_;
    const u16* Bbase = BT + (size_t)bh * D_ * N_;
    f32x4 acc[4] = {};
    int wrow = w * 16;
    int fr = l & 15, fq = l >> 4;
    for (int k0 = 0; k0 < N_; k0 += 64) {
        stage_tile(Abase + k0, N_, As, 64, w, l);
        stage_tile(Bbase + k0, N_, Bs, 64, w, l);
        __syncthreads();
        #pragma unroll
        for (int kk = 0; kk < 64; kk += 32) {
            bf16x8 af = frag_ld(As, wrow + fr, kk + fq * 8);
            bf16x8 bfr[4];
            #pragma unroll
            for (int j = 0; j < 4; j++) bfr[j] = frag_ld(Bs, j * 16 + fr, kk + fq * 8);
            #pragma unroll
            for (int j = 0; j < 4; j++)
                acc[j] = mfma_bf16(af, bfr[j], acc[j]);
        }
        __syncthreads();
    }
    float lam = (MODE == 0) ? lamb[h] : 0.f;
    #pragma unroll
    for (int j = 0; j < 4; j++) {
        int col = j * 16 + fr;
        int rowb = tm * 64 + wrow + fq * 4;
        if (MODE == 0) {
            ushort4 vv = *(const ushort4*)(BT + ((size_t)bh * D_ + col) * N_ + rowb);
            ushort4 zo;
            #pragma unroll
            for (int r = 0; r < 4; r++) {
                float zv = (1.f - 2.f * lam) * b2f(((const u16*)&vv)[r])
                         + 3.f * lam * acc[j][r];
                ((u16*)&zo)[r] = f2b(zv);
            }
            *(ushort4*)(outp + ((size_t)bh * D_ + col) * N_ + rowb) = zo;   // zT[d][n]
        } else {
            #pragma unroll
            for (int r = 0; r < 4; r++)
                outp[(size_t)(b * N_ + rowb + r) * C_ + h * 64 + col] = f2b(acc[j][r]);
        }
    }
}

// ---------------- GEMM: out = o @ W_proj + b_proj (f32 out) ----------------

__global__ __launch_bounds__(256, 2)
void k_gemm_proj(const u16* __restrict__ o, const u16* __restrict__ WT,
                 const float* __restrict__ bias, float* __restrict__ out) {
    __shared__ __attribute__((aligned(128))) u16 As[128 * 64];
    __shared__ __attribute__((aligned(128))) u16 Bs[128 * 64];
    int tid = threadIdx.x, w = tid >> 6, l = tid & 63;
    int swz = (blockIdx.x & 7) * 24 + (blockIdx.x >> 3);    // bijective (192%8==0)
    int row0 = (swz / 6) * 128, col0 = (swz % 6) * 128;
    f32x4 acc[4][4] = {};
    int wr = (w >> 1) * 64, wc = (w & 1) * 64;
    int fr = l & 15, fq = l >> 4;
    for (int k0 = 0; k0 < C_; k0 += 64) {
        stage_tile(o + (size_t)row0 * C_ + k0, C_, As, 128, w, l);
        stage_tile(WT + (size_t)col0 * C_ + k0, C_, Bs, 128, w, l);
        __syncthreads();
        #pragma unroll
        for (int kk = 0; kk < 64; kk += 32) {
            bf16x8 af[4], bfr[4];
            #pragma unroll
            for (int i = 0; i < 4; i++) af[i] = frag_ld(As, wr + i * 16 + fr, kk + fq * 8);
            #pragma unroll
            for (int j = 0; j < 4; j++) bfr[j] = frag_ld(Bs, wc + j * 16 + fr, kk + fq * 8);
            #pragma unroll
            for (int i = 0; i < 4; i++)
                #pragma unroll
                for (int j = 0; j < 4; j++)
                    acc[i][j] = mfma_bf16(af[i], bfr[j], acc[i][j]);
        }
        __syncthreads();
    }
    #pragma unroll
    for (int i = 0; i < 4; i++) {
        #pragma unroll
        for (int j = 0; j < 4; j++) {
            int col = col0 + wc + j * 16 + fr;
            float bv = bias[col];
            #pragma unroll
            for (int r = 0; r < 4; r++) {
                int row = row0 + wr + i * 16 + fq * 4 + r;
                out[(size_t)row * C_ + col] = acc[i][j][r] + bv;
            }
        }
    }
}

// ---------------- launch ----------------

extern "C" void kernel_launch(void* const* d_in, const int* in_sizes, int n_in,
                              void* d_out, int out_size, void* d_ws, size_t ws_size,
                              hipStream_t stream) {
    const float* x     = (const float*)d_in[0];
    const float* Wqkv  = (const float*)d_in[1];
    const float* Wproj = (const float*)d_in[2];
    const float* bproj = (const float*)d_in[3];
    const float* Wl    = (const float*)d_in[4];
    // d_in[5] = b_l: softmax-invariant, unused
    const float* Ww    = (const float*)d_in[6];
    const float* bw    = (const float*)d_in[7];
    const float* lamb  = (const float*)d_in[8];
    float* out = (float*)d_out;
    char* ws = (char*)d_ws;

    constexpr size_t SZ_S   = (size_t)B_ * N_ * H_ * N_ * 2;   // region (S8 uses half)
    constexpr size_t SZ_QK  = (size_t)B_ * N_ * 2 * C_ * 2;    //  12,582,912 (q,k only)
    constexpr size_t SZ_QKV = (size_t)B_ * N_ * 3 * C_ * 2;    //  18,874,368 (region size)
    constexpr size_t SZ_U   = (size_t)B_ * H_ * N_ * D_ * 2;   //   6,291,456
    constexpr size_t SZ_XB  = (size_t)B_ * N_ * C_ * 2;        //   6,291,456
    constexpr size_t SZ_WQT = (size_t)C_ * 3 * C_ * 2;         //   3,538,944

    u8*  S8     = (u8*)(ws);                            // 50MB (fp8)
    u16* zT     = (u16*)(ws);                           // reuse: S dead after mix
    u16* o      = (u16*)(ws + SZ_U);                    // reuse: inside dead S region
    u16* Pw     = (u16*)(ws + SZ_S);
    u16* qkv    = (u16*)(ws + 2 * SZ_S);                // [4096][1536] q,k
    u16* vT     = (u16*)(ws + 2 * SZ_S + SZ_QK);        // fits in old qkv region
    u16* xb     = (u16*)(ws + 2 * SZ_S + SZ_QKV);
    u16* WqkvT  = (u16*)(ws + 2 * SZ_S + SZ_QKV + SZ_XB);
    u16* WprojT = (u16*)(ws + 2 * SZ_S + SZ_QKV + SZ_XB + SZ_WQT);
    // footprint: ~220.5 MiB (unchanged)

    k_prep<<<5376, 256, 0, stream>>>(x, xb, Wqkv, WqkvT, Wproj, WprojT);
    k_gemm_qkv<<<576, 256, 0, stream>>>(xb, WqkvT, qkv, vT);
    k_gemm_qk<<<B_ * H_ * 64, 256, 0, stream>>>(qkv, S8);
    k_mix_softmax<<<B_ * N_, 256, 0, stream>>>(S8, Pw, Wl, Ww, bw);
    k_gemm_av<0><<<B_ * H_ * 16, 256, 0, stream>>>(Pw, vT, zT, lamb);
    k_gemm_av<1><<<B_ * H_ * 16, 256, 0, stream>>>(Pw, zT, o, nullptr);
    k_gemm_proj<<<192, 256, 0, stream>>>(o, WprojT, bproj, out);
}

// Round 20
// 142.705 us; speedup vs baseline: 1.0090x; 1.0090x over previous
//
#include <hip/hip_runtime.h>
#include <hip/hip_bf16.h>
#include <stdint.h>

#define B_ 4
#define N_ 1024
#define C_ 768
#define H_ 12
#define D_ 64

typedef unsigned short u16;
typedef unsigned char u8;
typedef __attribute__((ext_vector_type(8))) short bf16x8;
typedef __attribute__((ext_vector_type(4))) float f32x4;

#define AS1 __attribute__((address_space(1)))
#define AS3 __attribute__((address_space(3)))

__device__ __forceinline__ u16 f2b(float f) {
    union { float f; uint32_t u; } x; x.f = f;
    uint32_t r = x.u + 0x7fffu + ((x.u >> 16) & 1u);
    return (u16)(r >> 16);
}
__device__ __forceinline__ float b2f(u16 b) {
    union { uint32_t u; float f; } x; x.u = ((uint32_t)b) << 16;
    return x.f;
}
// packed f32->bf16 pair (RNE, same as f2b); dst.lo=cvt(lo), dst.hi=cvt(hi)
__device__ __forceinline__ uint32_t cvtpk(float lo, float hi) {
    uint32_t r;
    asm("v_cvt_pk_bf16_f32 %0, %1, %2" : "=v"(r) : "v"(lo), "v"(hi));
    return r;
}
// raw 2^x: one v_exp_f32 (no libm denormal fixup, no mul). Valid: |x| small.
__device__ __forceinline__ float exp2_fast(float x) {
    float r;
    asm("v_exp_f32 %0, %1" : "=v"(r) : "v"(x));
    return r;
}

__device__ __forceinline__ void gload16(const void* g, void* lds) {
    __builtin_amdgcn_global_load_lds((const AS1 uint32_t*)g, (AS3 uint32_t*)lds, 16, 0, 0);
}

// Stage a (rows x 64) bf16 tile from row-major src (leading dim ld, elements)
// into LDS. LDS layout: row stride 128B, 16B-slot XOR-swizzle byte^=(row&7)<<4.
__device__ __forceinline__ void stage_tile(const u16* __restrict__ g, int ld,
                                           u16* lds, int rows, int w, int l) {
    int nchunk = rows >> 3;              // 1KB chunks (8 rows each)
    for (int j = w; j < nchunk; j += 4) {
        int base = j << 10;              // wave-uniform LDS byte base
        int lanebyte = base + (l << 4);
        int row  = lanebyte >> 7;
        int slot = ((lanebyte >> 4) & 7) ^ (row & 7);
        const u16* src = g + row * ld + (slot << 3);
        gload16(src, (char*)lds + base);
    }
}

__device__ __forceinline__ bf16x8 frag_ld(const u16* lds, int row, int k) {
    int byte = (row << 7) + (k << 1);
    byte ^= (row & 7) << 4;
    return *(const bf16x8*)((const char*)lds + byte);
}

__device__ __forceinline__ f32x4 mfma_bf16(bf16x8 a, bf16x8 b, f32x4 c) {
    return __builtin_amdgcn_mfma_f32_16x16x32_bf16(a, b, c, 0, 0, 0);
}

// ---------------- merged input prep: cvt(x) + transcvt(Wqkv) + transcvt(Wproj) --

__global__ void k_prep(const float* __restrict__ x, u16* __restrict__ xb,
                       const float* __restrict__ Wqkv, u16* __restrict__ WqkvT,
                       const float* __restrict__ Wproj, u16* __restrict__ WprojT) {
    __shared__ float t[32][33];
    int blk = blockIdx.x;
    int tid = threadIdx.x;
    if (blk < 3072) {                    // cvt: x f32 -> xb bf16
        int i = blk * 256 + tid;
        float4 v = ((const float4*)x)[i];
        ushort4 o;
        o.x = f2b(v.x); o.y = f2b(v.y); o.z = f2b(v.z); o.w = f2b(v.w);
        ((ushort4*)xb)[i] = o;
        return;
    }
    const float* in; u16* outb; int R, Cc, bx, by;
    if (blk < 3072 + 1728) {             // Wqkv [768][2304] -> [2304][768] bf16
        int tq = blk - 3072;
        in = Wqkv; outb = WqkvT; R = C_; Cc = 3 * C_; bx = tq % 72; by = tq / 72;
    } else {                             // Wproj [768][768] -> transposed bf16
        int tq = blk - 4800;
        in = Wproj; outb = WprojT; R = C_; Cc = C_; bx = tq % 24; by = tq / 24;
    }
    int bc = bx * 32, br = by * 32;
    for (int i = 0; i < 4; i++) {
        int idx = i * 256 + tid; int r = idx >> 5, c = idx & 31;
        t[r][c] = in[(size_t)(br + r) * Cc + bc + c];
    }
    __syncthreads();
    for (int i = 0; i < 4; i++) {
        int idx = i * 256 + tid; int c = idx >> 5, r = idx & 31;
        outb[(size_t)(bc + c) * R + br + r] = f2b(t[r][c]);
    }
}

// ---------------- GEMM: qkv = x @ W_qkv ----------------
// qkv buffer holds ONLY q,k (ld = 2C, q pre-scaled by 1/8). v-columns
// (col >= 2C, block-uniform branch) are written DIRECTLY TRANSPOSED to
// vT[b][h][dd][n] via ushort4 -- no separate transpose kernel.

__global__ __launch_bounds__(256, 2)
void k_gemm_qkv(const u16* __restrict__ xb, const u16* __restrict__ WT,
                u16* __restrict__ qkv, u16* __restrict__ vT) {
    __shared__ __attribute__((aligned(128))) u16 As[128 * 64];
    __shared__ __attribute__((aligned(128))) u16 Bs[128 * 64];
    int tid = threadIdx.x, w = tid >> 6, l = tid & 63;
    int swz = (blockIdx.x & 7) * 72 + (blockIdx.x >> 3);    // bijective (576%8==0)
    int row0 = (swz / 18) * 128, col0 = (swz % 18) * 128;
    f32x4 acc[4][4] = {};
    int wr = (w >> 1) * 64, wc = (w & 1) * 64;
    int fr = l & 15, fq = l >> 4;
    for (int k0 = 0; k0 < C_; k0 += 64) {
        stage_tile(xb + (size_t)row0 * C_ + k0, C_, As, 128, w, l);
        stage_tile(WT + (size_t)col0 * C_ + k0, C_, Bs, 128, w, l);
        __syncthreads();
        #pragma unroll
        for (int kk = 0; kk < 64; kk += 32) {
            bf16x8 af[4], bfr[4];
            #pragma unroll
            for (int i = 0; i < 4; i++) af[i] = frag_ld(As, wr + i * 16 + fr, kk + fq * 8);
            #pragma unroll
            for (int j = 0; j < 4; j++) bfr[j] = frag_ld(Bs, wc + j * 16 + fr, kk + fq * 8);
            #pragma unroll
            for (int i = 0; i < 4; i++)
                #pragma unroll
                for (int j = 0; j < 4; j++)
                    acc[i][j] = mfma_bf16(af[i], bfr[j], acc[i][j]);
        }
        __syncthreads();
    }
    #pragma unroll
    for (int i = 0; i < 4; i++) {
        #pragma unroll
        for (int j = 0; j < 4; j++) {
            int col = col0 + wc + j * 16 + fr;
            int rowb = row0 + wr + i * 16 + fq * 4;
            if (col < 2 * C_) {                     // q,k -> qkv (ld 2C)
                float s = (col < C_) ? 0.125f : 1.0f;
                #pragma unroll
                for (int r = 0; r < 4; r++)
                    qkv[(size_t)(rowb + r) * (2 * C_) + col] = f2b(acc[i][j][r] * s);
            } else {                                // v -> vT transposed
                int col1 = col - 2 * C_;
                int hh = col1 >> 6, dd = col1 & 63;
                int bb = rowb >> 10, n0 = rowb & 1023;
                ushort4 vv;
                #pragma unroll
                for (int r = 0; r < 4; r++) ((u16*)&vv)[r] = f2b(acc[i][j][r]);
                *(ushort4*)(vT + ((size_t)(bb * H_ + hh) * D_ + dd) * N_ + n0) = vv;
            }
        }
    }
}

// ---------------- GEMM: S[b][n][h][m] = q . k  (S in FP8 e4m3) ----------------
// S values are tiny (sigma ~0.3, |S| <= ~2): e4m3 rel-err ~6%, and mix1
// multiplies by Wl~0.02 -> logit error ~0.01 abs -> negligible on softmax
// (validated r17: absmax unchanged at 0.03125). r18 lesson: fp8 is
// admissible ONLY here (softmax-damped); Pw/z must stay bf16 (direct path).

__global__ __launch_bounds__(256, 2)
void k_gemm_qk(const u16* __restrict__ qkv, u8* __restrict__ S8) {
    __shared__ __attribute__((aligned(128))) u16 pool[128 * 132];   // 33.8KB
    u16* As = pool;
    u16* Bs = pool + 128 * 64;
    int tid = threadIdx.x, w = tid >> 6, l = tid & 63;
    int blk = (blockIdx.x & 7) * 384 + (blockIdx.x >> 3);   // bijective (3072%8==0)
    int bh = blk >> 6, t = blk & 63;
    int b = bh / H_, h = bh % H_;
    int tm = t >> 3, tn = t & 7;
    const u16* qbase = qkv + (size_t)(b * N_) * (2 * C_) + h * 64;
    const u16* kbase = qkv + (size_t)(b * N_) * (2 * C_) + C_ + h * 64;
    f32x4 acc[4][4] = {};
    int wr = (w >> 1) * 64, wc = (w & 1) * 64;
    int fr = l & 15, fq = l >> 4;
    stage_tile(qbase + (size_t)(tm * 128) * (2 * C_), 2 * C_, As, 128, w, l);
    stage_tile(kbase + (size_t)(tn * 128) * (2 * C_), 2 * C_, Bs, 128, w, l);
    __syncthreads();
    #pragma unroll
    for (int kk = 0; kk < 64; kk += 32) {
        bf16x8 af[4], bfr[4];
        #pragma unroll
        for (int i = 0; i < 4; i++) af[i] = frag_ld(As, wr + i * 16 + fr, kk + fq * 8);
        #pragma unroll
        for (int j = 0; j < 4; j++) bfr[j] = frag_ld(Bs, wc + j * 16 + fr, kk + fq * 8);
        #pragma unroll
        for (int i = 0; i < 4; i++)
            #pragma unroll
            for (int j = 0; j < 4; j++)
                acc[i][j] = mfma_bf16(af[i], bfr[j], acc[i][j]);
    }
    __syncthreads();                       // all frag ds_reads done; reuse pool
    u8* Cs = (u8*)pool;                    // [128][136] u8 (8B-aligned rows)
    #pragma unroll
    for (int i = 0; i < 4; i++) {
        #pragma unroll
        for (int j = 0; j < 4; j++) {
            int lcol = wc + j * 16 + fr;
            int lrow0 = wr + i * 16 + fq * 4;
            uint32_t w01 = __builtin_amdgcn_cvt_pk_fp8_f32(acc[i][j][0], acc[i][j][1], 0, false);
            uint32_t w23 = __builtin_amdgcn_cvt_pk_fp8_f32(acc[i][j][2], acc[i][j][3], 0, false);
            Cs[(lrow0 + 0) * 136 + lcol] = (u8)w01;
            Cs[(lrow0 + 1) * 136 + lcol] = (u8)(w01 >> 8);
            Cs[(lrow0 + 2) * 136 + lcol] = (u8)w23;
            Cs[(lrow0 + 3) * 136 + lcol] = (u8)(w23 >> 8);
        }
    }
    __syncthreads();
    // 128 rows x 16 8B-chunks = 2048 chunks / 256 thr = 8 passes
    for (int q = 0; q < 8; q++) {
        int idx = q * 256 + tid;
        int lrow = idx >> 4, lc = idx & 15;
        uint2 v = *(const uint2*)&Cs[lrow * 136 + lc * 8];
        *(uint2*)(S8 + ((size_t)(b * N_ + tm * 128 + lrow) * H_ + h) * N_
                     + tn * 128 + lc * 8) = v;
    }
}

// ---------------- fused: W_l head-mix + softmax + W_w head-mix ----------------
// Final form (= r17, best measured): 4 waves/block per (b,n); wave wv owns
// m-range [wv*256,+256). Staging packs raw fp8 bytes into per-wave LDS
// planes. mix1 = mfma_f32_16x16x32_fp8_fp8 (A1 = Wl^T*log2e fp8, zero-pad);
// E = 2^T via raw v_exp_f32 stays in registers; C<->B duality (4 __shfl)
// feeds mix2 (bf16 MFMA); A2 = Ww^T/Z_h; bias via C-init; b_l dropped
// (softmax-invariant); no max-subtraction (logits bounded, validated).

__global__ __launch_bounds__(256)
void k_mix_softmax(const u8* __restrict__ S8, u16* __restrict__ Pw,
                   const float* __restrict__ Wl, const float* __restrict__ Ww,
                   const float* __restrict__ bw) {
    __shared__ __attribute__((aligned(16))) char mixpool[4][8192];  // 32KB
    __shared__ float Zl[4][16];
    __shared__ float sWl[144], sWw[144], sbw16[16];
    int tid = threadIdx.x;
    int wv = tid >> 6, l = tid & 63;
    int m_l = l & 15, gr = l >> 4;
    if (tid < 144) { sWl[tid] = Wl[tid]; sWw[tid] = Ww[tid]; }
    if (tid < 16) sbw16[tid] = (tid < 12) ? bw[tid] : 0.f;
    __syncthreads();

    int blk = blockIdx.x;
    int b = blk >> 10, n = blk & 1023;
    const u8* srow = S8 + ((size_t)(b * N_ + n) * H_) * N_ + wv * 256;
    char* wvbase = &mixpool[wv][0];

    // ---- staging: lane l covers m = p*64+l; one b64 (8 fp8) per (m, plane) ----
    for (int p = 0; p < 4; p++) {
        int m = p * 64 + l;
        #pragma unroll
        for (int hb = 0; hb < 2; hb++) {
            uint2 pk;
            u8* pb = (u8*)&pk;
            #pragma unroll
            for (int j = 0; j < 8; j++) {
                int h = hb * 8 + j;
                pb[j] = (h < 12) ? srow[(size_t)h * N_ + m] : (u8)0;
            }
            *(uint2*)(wvbase + hb * 2048 + m * 8) = pk;
        }
    }

    // A1 frag: Wl^T * log2e in fp8, zero-padded to 16x32 (k = byte index)
    float wv8[8];
    #pragma unroll
    for (int j = 0; j < 8; j++) {
        int h = gr * 8 + j;
        int ok = (m_l < 12) & (h < 12);
        wv8[j] = ok ? (sWl[ok ? (h * 12 + m_l) : 0] * 1.44269504089f) : 0.f;
    }
    uint32_t a1lo = 0, a1hi = 0;
    a1lo = __builtin_amdgcn_cvt_pk_fp8_f32(wv8[0], wv8[1], a1lo, false);
    a1lo = __builtin_amdgcn_cvt_pk_fp8_f32(wv8[2], wv8[3], a1lo, true);
    a1hi = __builtin_amdgcn_cvt_pk_fp8_f32(wv8[4], wv8[5], a1hi, false);
    a1hi = __builtin_amdgcn_cvt_pk_fp8_f32(wv8[6], wv8[7], a1hi, true);
    long a1 = ((long)a1hi << 32) | (long)a1lo;

    // mix1 (fp8 MFMA) + 2^x + Z-accumulate; E kept in registers (bf16 pairs)
    float z0 = 0.f, z1 = 0.f, z2 = 0.f, z3 = 0.f;
    uint32_t E0[16], E1[16];
    #pragma unroll
    for (int grp = 0; grp < 16; grp++) {
        long bs = 0;
        if (gr < 2) bs = *(const long*)(wvbase + gr * 2048 + (grp * 16 + m_l) * 8);
        f32x4 c = {0.f, 0.f, 0.f, 0.f};
        c = __builtin_amdgcn_mfma_f32_16x16x32_fp8_fp8(a1, bs, c, 0, 0, 0);
        float e0 = exp2_fast(c[0]), e1 = exp2_fast(c[1]);
        float e2 = exp2_fast(c[2]), e3 = exp2_fast(c[3]);
        z0 += e0; z1 += e1; z2 += e2; z3 += e3;
        E0[grp] = cvtpk(e0, e1);
        E1[grp] = cvtpk(e2, e3);
    }

    // Z: reduce over 16 m-lanes, publish per-wave, sum across waves
    #pragma unroll
    for (int off = 1; off < 16; off <<= 1) {
        z0 += __shfl_xor(z0, off);
        z1 += __shfl_xor(z1, off);
        z2 += __shfl_xor(z2, off);
        z3 += __shfl_xor(z3, off);
    }
    if (m_l == 0) {
        Zl[wv][gr * 4 + 0] = z0; Zl[wv][gr * 4 + 1] = z1;
        Zl[wv][gr * 4 + 2] = z2; Zl[wv][gr * 4 + 3] = z3;
    }
    __syncthreads();

    // A2 frag: Ww^T / Z_h, zero-padded (bf16 -- mix2 unchanged)
    bf16x8 a2;
    #pragma unroll
    for (int j = 0; j < 8; j++) {
        int h = gr * 8 + j;
        float v = 0.f;
        if ((m_l < 12) & (h < 12)) {
            float zz = Zl[0][h] + Zl[1][h] + Zl[2][h] + Zl[3][h];
            v = sWw[h * 12 + m_l] / zz;
        }
        ((u16*)&a2)[j] = f2b(v);
    }

    // mix2: B-frag gathered from E regs via 4 shuffles (C<->B duality)
    f32x4 cb;
    cb[0] = sbw16[gr * 4 + 0]; cb[1] = sbw16[gr * 4 + 1];
    cb[2] = sbw16[gr * 4 + 2]; cb[3] = sbw16[gr * 4 + 3];
    int la = m_l + (((2 * gr) & 3) << 4);
    int lb = m_l + (((2 * gr + 1) & 3) << 4);
    u16* Pb = (u16*)wvbase;                    // overlay: staging dead after mix1
    #pragma unroll
    for (int grp = 0; grp < 16; grp++) {
        union { int4 i4; bf16x8 v; } u;
        u.i4.x = __shfl((int)E0[grp], la);
        u.i4.y = __shfl((int)E1[grp], la);
        u.i4.z = __shfl((int)E0[grp], lb);
        u.i4.w = __shfl((int)E1[grp], lb);
        f32x4 c = cb;
        c = mfma_bf16(a2, u.v, c);
        if (gr < 3) {
            uint32_t w01 = cvtpk(c[0], c[1]);
            uint32_t w23 = cvtpk(c[2], c[3]);
            int g0 = gr * 4, mm = grp * 16 + m_l;
            Pb[(g0 + 0) * 276 + mm] = (u16)w01;
            Pb[(g0 + 1) * 276 + mm] = (u16)(w01 >> 16);
            Pb[(g0 + 2) * 276 + mm] = (u16)w23;
            Pb[(g0 + 3) * 276 + mm] = (u16)(w23 >> 16);
        }
    }

    // vectorized Pw store: 12 rows x 512B per wave (wave-local, no barrier)
    for (int g = 0; g < 12; g++) {
        ushort4 v = *(const ushort4*)&Pb[g * 276 + l * 4];
        *(ushort4*)(Pw + ((size_t)(b * H_ + g) * N_ + n) * N_ + wv * 256 + l * 4) = v;
    }
}

// ---------------- GEMM: MODE 0: u = Pw @ v, epilogue z = (1-2l)v + 3l*u -> zT
//                        MODE 1: o = Pw @ z (B = zT), writes o[b,n,h*64+d] ----------------
// algebra: out_head = (1-2l)*Pw@v + 3l*Pw@(Pw@v) = Pw @ z,  z=(1-2l)v+3l*u
// 64-row tiles (tm 0..15): grid 768 blocks, LDS 16KB, ~3 blocks/CU.
// XCD-aware chunked swizzle (T1, proven r15). bf16 throughout (r18 lesson).

template <int MODE>
__global__ __launch_bounds__(256, 2)
void k_gemm_av(const u16* __restrict__ Pw, const u16* __restrict__ BT,
               u16* __restrict__ outp, const float* __restrict__ lamb) {
    __shared__ __attribute__((aligned(128))) u16 As[64 * 64];
    __shared__ __attribute__((aligned(128))) u16 Bs[64 * 64];
    int tid = threadIdx.x, w = tid >> 6, l = tid & 63;
    int blk = (blockIdx.x & 7) * 96 + (blockIdx.x >> 3);    // bijective (768%8==0)
    int bh = blk >> 4, tm = blk & 15;
    int b = bh / H_, h = bh % H_;
    const u16* Abase = Pw + ((size_t)bh * N_ + tm * 64) * N_;
    const u16* Bbase = BT + (size_t)bh * D_ * N_;
    f32x4 acc[4] = {};
    int wrow = w * 16;
    int fr = l & 15, fq = l >> 4;
    for (int k0 = 0; k0 < N_; k0 += 64) {
        stage_tile(Abase + k0, N_, As, 64, w, l);
        stage_tile(Bbase + k0, N_, Bs, 64, w, l);
        __syncthreads();
        #pragma unroll
        for (int kk = 0; kk < 64; kk += 32) {
            bf16x8 af = frag_ld(As, wrow + fr, kk + fq * 8);
            bf16x8 bfr[4];
            #pragma unroll
            for (int j = 0; j < 4; j++) bfr[j] = frag_ld(Bs, j * 16 + fr, kk + fq * 8);
            #pragma unroll
            for (int j = 0; j < 4; j++)
                acc[j] = mfma_bf16(af, bfr[j], acc[j]);
        }
        __syncthreads();
    }
    float lam = (MODE == 0) ? lamb[h] : 0.f;
    #pragma unroll
    for (int j = 0; j < 4; j++) {
        int col = j * 16 + fr;
        int rowb = tm * 64 + wrow + fq * 4;
        if (MODE == 0) {
            ushort4 vv = *(const ushort4*)(BT + ((size_t)bh * D_ + col) * N_ + rowb);
            ushort4 zo;
            #pragma unroll
            for (int r = 0; r < 4; r++) {
                float zv = (1.f - 2.f * lam) * b2f(((const u16*)&vv)[r])
                         + 3.f * lam * acc[j][r];
                ((u16*)&zo)[r] = f2b(zv);
            }
            *(ushort4*)(outp + ((size_t)bh * D_ + col) * N_ + rowb) = zo;   // zT[d][n]
        } else {
            #pragma unroll
            for (int r = 0; r < 4; r++)
                outp[(size_t)(b * N_ + rowb + r) * C_ + h * 64 + col] = f2b(acc[j][r]);
        }
    }
}

// ---------------- GEMM: out = o @ W_proj + b_proj (f32 out) ----------------

__global__ __launch_bounds__(256, 2)
void k_gemm_proj(const u16* __restrict__ o, const u16* __restrict__ WT,
                 const float* __restrict__ bias, float* __restrict__ out) {
    __shared__ __attribute__((aligned(128))) u16 As[128 * 64];
    __shared__ __attribute__((aligned(128))) u16 Bs[128 * 64];
    int tid = threadIdx.x, w = tid >> 6, l = tid & 63;
    int swz = (blockIdx.x & 7) * 24 + (blockIdx.x >> 3);    // bijective (192%8==0)
    int row0 = (swz / 6) * 128, col0 = (swz % 6) * 128;
    f32x4 acc[4][4] = {};
    int wr = (w >> 1) * 64, wc = (w & 1) * 64;
    int fr = l & 15, fq = l >> 4;
    for (int k0 = 0; k0 < C_; k0 += 64) {
        stage_tile(o + (size_t)row0 * C_ + k0, C_, As, 128, w, l);
        stage_tile(WT + (size_t)col0 * C_ + k0, C_, Bs, 128, w, l);
        __syncthreads();
        #pragma unroll
        for (int kk = 0; kk < 64; kk += 32) {
            bf16x8 af[4], bfr[4];
            #pragma unroll
            for (int i = 0; i < 4; i++) af[i] = frag_ld(As, wr + i * 16 + fr, kk + fq * 8);
            #pragma unroll
            for (int j = 0; j < 4; j++) bfr[j] = frag_ld(Bs, wc + j * 16 + fr, kk + fq * 8);
            #pragma unroll
            for (int i = 0; i < 4; i++)
                #pragma unroll
                for (int j = 0; j < 4; j++)
                    acc[i][j] = mfma_bf16(af[i], bfr[j], acc[i][j]);
        }
        __syncthreads();
    }
    #pragma unroll
    for (int i = 0; i < 4; i++) {
        #pragma unroll
        for (int j = 0; j < 4; j++) {
            int col = col0 + wc + j * 16 + fr;
            float bv = bias[col];
            #pragma unroll
            for (int r = 0; r < 4; r++) {
                int row = row0 + wr + i * 16 + fq * 4 + r;
                out[(size_t)row * C_ + col] = acc[i][j][r] + bv;
            }
        }
    }
}

// ---------------- launch ----------------

extern "C" void kernel_launch(void* const* d_in, const int* in_sizes, int n_in,
                              void* d_out, int out_size, void* d_ws, size_t ws_size,
                              hipStream_t stream) {
    const float* x     = (const float*)d_in[0];
    const float* Wqkv  = (const float*)d_in[1];
    const float* Wproj = (const float*)d_in[2];
    const float* bproj = (const float*)d_in[3];
    const float* Wl    = (const float*)d_in[4];
    // d_in[5] = b_l: softmax-invariant, unused
    const float* Ww    = (const float*)d_in[6];
    const float* bw    = (const float*)d_in[7];
    const float* lamb  = (const float*)d_in[8];
    float* out = (float*)d_out;
    char* ws = (char*)d_ws;

    constexpr size_t SZ_S   = (size_t)B_ * N_ * H_ * N_ * 2;   // region (S8 uses half)
    constexpr size_t SZ_QK  = (size_t)B_ * N_ * 2 * C_ * 2;    //  12,582,912 (q,k only)
    constexpr size_t SZ_QKV = (size_t)B_ * N_ * 3 * C_ * 2;    //  18,874,368 (region size)
    constexpr size_t SZ_U   = (size_t)B_ * H_ * N_ * D_ * 2;   //   6,291,456
    constexpr size_t SZ_XB  = (size_t)B_ * N_ * C_ * 2;        //   6,291,456
    constexpr size_t SZ_WQT = (size_t)C_ * 3 * C_ * 2;         //   3,538,944

    u8*  S8     = (u8*)(ws);                            // 50MB (fp8)
    u16* zT     = (u16*)(ws);                           // reuse: S dead after mix
    u16* o      = (u16*)(ws + SZ_U);                    // reuse: inside dead S region
    u16* Pw     = (u16*)(ws + SZ_S);
    u16* qkv    = (u16*)(ws + 2 * SZ_S);                // [4096][1536] q,k
    u16* vT     = (u16*)(ws + 2 * SZ_S + SZ_QK);        // fits in old qkv region
    u16* xb     = (u16*)(ws + 2 * SZ_S + SZ_QKV);
    u16* WqkvT  = (u16*)(ws + 2 * SZ_S + SZ_QKV + SZ_XB);
    u16* WprojT = (u16*)(ws + 2 * SZ_S + SZ_QKV + SZ_XB + SZ_WQT);
    // footprint: ~220.5 MiB (unchanged)

    k_prep<<<5376, 256, 0, stream>>>(x, xb, Wqkv, WqkvT, Wproj, WprojT);
    k_gemm_qkv<<<576, 256, 0, stream>>>(xb, WqkvT, qkv, vT);
    k_gemm_qk<<<B_ * H_ * 64, 256, 0, stream>>>(qkv, S8);
    k_mix_softmax<<<B_ * N_, 256, 0, stream>>>(S8, Pw, Wl, Ww, bw);
    k_gemm_av<0><<<B_ * H_ * 16, 256, 0, stream>>>(Pw, vT, zT, lamb);
    k_gemm_av<1><<<B_ * H_ * 16, 256, 0, stream>>>(Pw, zT, o, nullptr);
    k_gemm_proj<<<192, 256, 0, stream>>>(o, WprojT, bproj, out);
}